// Round 7
// baseline (423.218 us; speedup 1.0000x reference)
//
#include <hip/hip_runtime.h>
#include <hip/hip_bf16.h>

#define H 16
#define F_IN 58
#define NPB 16     // nodes per block in t0 (256 threads / 16 lanes)
#define SCH 4160   // max edges per stage chunk (LDS sort capacity)
#define ANPB 16    // nodes per agg block (256 threads / 16 lanes)
#define ECAP 1024  // LDS edge-cache capacity in agg (16 nodes * avg 32 = 512 typ)

static inline size_t align256(size_t x) { return (x + 255) & ~(size_t)255; }

__device__ inline float bf2f(__hip_bfloat16 h) { return __bfloat162float(h); }
__device__ inline float bfu2f(unsigned short u) {
    return __uint_as_float(((unsigned)u) << 16);
}

// ---------- dtype detection: int64 vs int32 edge_index ----------
__global__ void detect_kernel(const int* eidx32, int* flag) {
    __shared__ int any;
    if (threadIdx.x == 0) any = 0;
    __syncthreads();
    int nz = 0;
    for (int j = threadIdx.x; j < 1024; j += 256)
        nz |= (eidx32[2 * j + 1] != 0);
    if (nz) atomicOr(&any, 1);
    __syncthreads();
    if (threadIdx.x == 0) *flag = (any == 0) ? 1 : 0;  // all-zero odd words -> int64
}

__device__ inline int load_idx(const void* eidx, long i, int is64) {
    if (is64) return (int)((const long long*)eidx)[i];
    return ((const int*)eidx)[i];
}

// ---------- bucket counts (391 bins of 256 nodes) via LDS histogram ----------
__global__ void bcount_kernel(const void* eidx, int E, const int* flag64,
                              int n, int* bucketcnt) {
    __shared__ int hist[512];
    int is64 = *flag64;
    int B = (n + 255) >> 8;
    int tid = threadIdx.x;
    for (int j = tid; j < B; j += 256) hist[j] = 0;
    __syncthreads();
    int stride = gridDim.x * blockDim.x;
    for (int i = blockIdx.x * blockDim.x + tid; i < E; i += stride) {
        int d = load_idx(eidx, (long)E + i, is64);
        atomicAdd(&hist[d >> 8], 1);
    }
    __syncthreads();
    for (int j = tid; j < B; j += 256)
        if (hist[j]) atomicAdd(&bucketcnt[j], hist[j]);
}

// ---------- exclusive scan of bucket counts (single block, B <= 512) ----------
__global__ void bscan_kernel(const int* bucketcnt, int B, int E,
                             int* gcur, int* bucketbase) {
    __shared__ int tmp[512];
    int tid = threadIdx.x;
    int val = (tid < B) ? bucketcnt[tid] : 0;
    tmp[tid] = val;
    __syncthreads();
    for (int off = 1; off < 512; off <<= 1) {
        int t = (tid >= off) ? tmp[tid - off] : 0;
        __syncthreads();
        tmp[tid] += t;
        __syncthreads();
    }
    if (tid < B) {
        int ex = tmp[tid] - val;
        gcur[tid] = ex;
        bucketbase[tid] = ex;
    }
    if (tid == 0) bucketbase[B] = E;
}

// ---------- stage: LDS counting-sort each chunk by bucket, write coalesced runs ----------
__global__ void stage_kernel(const void* eidx, int E, const int* flag64,
                             int n, int* gcur, unsigned* staging) {
    __shared__ unsigned sorted[SCH];
    __shared__ unsigned short sbuck[SCH];
    __shared__ int hist[512];
    __shared__ int hbase[512];
    __shared__ int lofs[512];
    __shared__ int cursor[512];
    __shared__ int ps[256];

    int is64 = *flag64;
    int tid = threadIdx.x;
    int chunk = (E + gridDim.x - 1) / gridDim.x;
    int s0 = blockIdx.x * chunk;
    int s1 = min(E, s0 + chunk);
    int c = s1 - s0;
    if (c <= 0) return;

    for (int j = tid; j < 512; j += 256) { hist[j] = 0; cursor[j] = 0; }
    __syncthreads();

    // pass A: per-chunk bucket histogram
    for (int i = s0 + tid; i < s1; i += 256) {
        int d = load_idx(eidx, (long)E + i, is64);
        atomicAdd(&hist[d >> 8], 1);
    }
    __syncthreads();

    // pass B: reserve global run per bucket
    for (int j = tid; j < 512; j += 256) {
        int cc = hist[j];
        hbase[j] = cc ? atomicAdd(&gcur[j], cc) : 0;
    }

    // pass C: exclusive scan of hist -> lofs (512 bins, 256 threads)
    int a0 = hist[2 * tid], a1 = hist[2 * tid + 1];
    ps[tid] = a0 + a1;
    __syncthreads();
    for (int off = 1; off < 256; off <<= 1) {
        int t = (tid >= off) ? ps[tid - off] : 0;
        __syncthreads();
        ps[tid] += t;
        __syncthreads();
    }
    int ex = ps[tid] - (a0 + a1);
    lofs[2 * tid] = ex;
    lofs[2 * tid + 1] = ex + a0;
    __syncthreads();

    // pass D: scatter into LDS in bucket-sorted order
    for (int i = s0 + tid; i < s1; i += 256) {
        int s = load_idx(eidx, i, is64);
        int d = load_idx(eidx, (long)E + i, is64);
        int b = d >> 8;
        int loc = lofs[b] + atomicAdd(&cursor[b], 1);
        sorted[loc] = (unsigned)s | ((unsigned)(d & 255) << 17);
        sbuck[loc] = (unsigned short)b;
    }
    __syncthreads();

    // pass E: linear LDS read, coalesced run writes to global
    for (int i = tid; i < c; i += 256) {
        int b = sbuck[i];
        staging[hbase[b] + (i - lofs[b])] = sorted[i];
    }
}

// ---------- per-bucket local hist + scan -> rowstart/dinv, node-sorted ed ----------
__global__ void fine_kernel(const unsigned* __restrict__ staging,
                            const int* __restrict__ bucketbase, int n, int E,
                            int* __restrict__ ed, int* __restrict__ rowstart,
                            float* __restrict__ dinv) {
    __shared__ int lcnt[256];
    __shared__ int lofs[256];
    __shared__ int lcur[256];
    int tid = threadIdx.x;
    int b = blockIdx.x;
    int node0 = b << 8;
    int start = bucketbase[b], end = bucketbase[b + 1];
    int cnt = end - start;
    lcnt[tid] = 0;
    lcur[tid] = 0;
    __syncthreads();
    for (int i = tid; i < cnt; i += 256) {
        unsigned w = staging[start + i];
        atomicAdd(&lcnt[w >> 17], 1);
    }
    __syncthreads();
    int val = lcnt[tid];
    lofs[tid] = val;
    __syncthreads();
    for (int off = 1; off < 256; off <<= 1) {
        int t = (tid >= off) ? lofs[tid - off] : 0;
        __syncthreads();
        lofs[tid] += t;
        __syncthreads();
    }
    int ex = lofs[tid] - val;
    __syncthreads();
    lofs[tid] = ex;
    __syncthreads();
    int node = node0 + tid;
    if (node < n) {
        rowstart[node] = start + ex;
        dinv[node] = rsqrtf((float)(val + 1));
    }
    if (node == 0) rowstart[n] = E;
    for (int i = tid; i < cnt; i += 256) {
        unsigned w = staging[start + i];
        int ld = (int)(w >> 17);
        int pos = start + lofs[ld] + atomicAdd(&lcur[ld], 1);
        ed[pos] = (int)(w & 0x1FFFFu);
    }
}

// ---------- layer 0 dense transform: hw0 = bf16(dinv * (x @ W0)) ----------
__global__ void t0_kernel(const float* __restrict__ x, const float* __restrict__ W0,
                          const float* __restrict__ dinv,
                          __hip_bfloat16* __restrict__ hw, int n) {
    __shared__ float Wl[F_IN * H];
    int tid = threadIdx.x;
    for (int j = tid; j < F_IN * H; j += 256) Wl[j] = W0[j];
    __syncthreads();
    int g = tid >> 4, f = tid & 15;
    int v = blockIdx.x * NPB + g;
    if (v >= n) return;
    const float* xr = x + (long)v * F_IN;
    float acc = 0.f;
#pragma unroll
    for (int k = 0; k < F_IN; ++k) acc += xr[k] * Wl[k * H + f];
    hw[v * H + f] = __float2bfloat16(acc * dinv[v]);
}

// ---------- aggregation: 16 lanes/node = 4 edge-slots x 4 feature-quads ----------
// hw holds dinv-scaled features (bf16); agg = dinv[v]*(sum_src hw[src] + hw[v])
__global__ __launch_bounds__(256) void agg_kernel(
    const int* __restrict__ ed, const int* __restrict__ rowstart,
    const float* __restrict__ dinv, const __hip_bfloat16* __restrict__ hw,
    const float* __restrict__ bias, const float* __restrict__ Wnext,
    float* __restrict__ jk, __hip_bfloat16* __restrict__ hw_next,
    int n, int first, int has_next) {
    __shared__ float Wl[H * H];
    __shared__ int eds[ECAP];
    __shared__ int rs[ANPB + 1];
    int tid = threadIdx.x;
    if (has_next) Wl[tid] = Wnext[tid];  // 256 threads == 16x16
    int node0 = blockIdx.x * ANPB;
    int nn = min(ANPB, n - node0);       // nodes in this block (>=1)
    if (tid <= nn) rs[tid] = rowstart[node0 + tid];
    __syncthreads();
    int s0 = rs[0];
    int cnt = rs[nn] - s0;
    for (int i = tid; i < cnt && i < ECAP; i += 256) eds[i] = ed[s0 + i];
    __syncthreads();

    int g = tid >> 4;                    // node 0..15
    int l = tid & 15;
    int es = l >> 2;                     // edge slot 0..3
    int fb = (l & 3) * 4;                // feature quad base
    if (g >= nn) return;
    int v = node0 + g;
    const unsigned short* hwu = (const unsigned short*)hw;

    float4 acc = make_float4(0.f, 0.f, 0.f, 0.f);
    int ls = rs[g] - s0, le = rs[g + 1] - s0;
    bool inlds = (le <= ECAP);

    if (inlds) {
        for (int base = ls; base < le; base += 8) {
            int e0 = base + es, e1 = base + 4 + es;
            bool v0 = e0 < le, v1 = e1 < le;
            int t0 = v0 ? eds[e0] : 0;
            int t1 = v1 ? eds[e1] : 0;
            ushort4 u0, u1;
            if (v0) u0 = *(const ushort4*)(hwu + t0 * H + fb);
            if (v1) u1 = *(const ushort4*)(hwu + t1 * H + fb);
            if (v0) { acc.x += bfu2f(u0.x); acc.y += bfu2f(u0.y);
                      acc.z += bfu2f(u0.z); acc.w += bfu2f(u0.w); }
            if (v1) { acc.x += bfu2f(u1.x); acc.y += bfu2f(u1.y);
                      acc.z += bfu2f(u1.z); acc.w += bfu2f(u1.w); }
        }
    } else {
        for (int base = ls; base < le; base += 8) {
            int e0 = base + es, e1 = base + 4 + es;
            bool v0 = e0 < le, v1 = e1 < le;
            int t0 = v0 ? ed[s0 + e0] : 0;
            int t1 = v1 ? ed[s0 + e1] : 0;
            ushort4 u0, u1;
            if (v0) u0 = *(const ushort4*)(hwu + t0 * H + fb);
            if (v1) u1 = *(const ushort4*)(hwu + t1 * H + fb);
            if (v0) { acc.x += bfu2f(u0.x); acc.y += bfu2f(u0.y);
                      acc.z += bfu2f(u0.z); acc.w += bfu2f(u0.w); }
            if (v1) { acc.x += bfu2f(u1.x); acc.y += bfu2f(u1.y);
                      acc.z += bfu2f(u1.z); acc.w += bfu2f(u1.w); }
        }
    }

    // butterfly reduce across the 4 edge slots (lanes ^4, ^8 within width 16)
    acc.x += __shfl_xor(acc.x, 4, 16); acc.y += __shfl_xor(acc.y, 4, 16);
    acc.z += __shfl_xor(acc.z, 4, 16); acc.w += __shfl_xor(acc.w, 4, 16);
    acc.x += __shfl_xor(acc.x, 8, 16); acc.y += __shfl_xor(acc.y, 8, 16);
    acc.z += __shfl_xor(acc.z, 8, 16); acc.w += __shfl_xor(acc.w, 8, 16);

    // self-loop + bias + relu (all lanes; es sub-quads redundant)
    ushort4 us = *(const ushort4*)(hwu + (size_t)v * H + fb);
    float dv = dinv[v];
    float4 val;
    val.x = fmaxf((acc.x + bfu2f(us.x)) * dv + bias[fb + 0], 0.f);
    val.y = fmaxf((acc.y + bfu2f(us.y)) * dv + bias[fb + 1], 0.f);
    val.z = fmaxf((acc.z + bfu2f(us.z)) * dv + bias[fb + 2], 0.f);
    val.w = fmaxf((acc.w + bfu2f(us.w)) * dv + bias[fb + 3], 0.f);

    // jk running max (es==0 lanes store; lanes 0..3 cover node's full 64B row)
    if (es == 0) {
        float4* jkp = (float4*)(jk + (size_t)v * H + fb);
        float4 jv = val;
        if (!first) {
            float4 jo = *jkp;
            jv.x = fmaxf(jo.x, val.x); jv.y = fmaxf(jo.y, val.y);
            jv.z = fmaxf(jo.z, val.z); jv.w = fmaxf(jo.w, val.w);
        }
        *jkp = jv;
    }

    // fused next-layer transform: out[f'] = sum_k val_all[k] * W[k][f']
    if (has_next) {
        float4 o = make_float4(0.f, 0.f, 0.f, 0.f);
#pragma unroll
        for (int kq = 0; kq < 4; ++kq) {
            float4 vk;
            vk.x = __shfl(val.x, kq, 4);
            vk.y = __shfl(val.y, kq, 4);
            vk.z = __shfl(val.z, kq, 4);
            vk.w = __shfl(val.w, kq, 4);
            float4 w0 = *(const float4*)(Wl + (4 * kq + 0) * H + fb);
            float4 w1 = *(const float4*)(Wl + (4 * kq + 1) * H + fb);
            float4 w2 = *(const float4*)(Wl + (4 * kq + 2) * H + fb);
            float4 w3 = *(const float4*)(Wl + (4 * kq + 3) * H + fb);
            o.x += vk.x * w0.x + vk.y * w1.x + vk.z * w2.x + vk.w * w3.x;
            o.y += vk.x * w0.y + vk.y * w1.y + vk.z * w2.y + vk.w * w3.y;
            o.z += vk.x * w0.z + vk.y * w1.z + vk.z * w2.z + vk.w * w3.z;
            o.w += vk.x * w0.w + vk.y * w1.w + vk.z * w2.w + vk.w * w3.w;
        }
        if (es == 0) {
            ushort4 ob;
            ob.x = (unsigned short)(__bfloat16_as_ushort(__float2bfloat16(o.x * dv)));
            ob.y = (unsigned short)(__bfloat16_as_ushort(__float2bfloat16(o.y * dv)));
            ob.z = (unsigned short)(__bfloat16_as_ushort(__float2bfloat16(o.z * dv)));
            ob.w = (unsigned short)(__bfloat16_as_ushort(__float2bfloat16(o.w * dv)));
            *(ushort4*)((unsigned short*)hw_next + (size_t)v * H + fb) = ob;
        }
    }
}

// ---------- final FC: out = jk @ fc_w + fc_b ----------
__global__ void fc_kernel(const float* __restrict__ jk, const float* __restrict__ fc_w,
                          const float* __restrict__ fc_b, float* __restrict__ out, int n) {
    __shared__ float w[H];
    __shared__ float b0;
    if (threadIdx.x < H) w[threadIdx.x] = fc_w[threadIdx.x];
    if (threadIdx.x == 0) b0 = fc_b[0];
    __syncthreads();
    int v = blockIdx.x * 256 + threadIdx.x;
    if (v >= n) return;
    const float4* r = (const float4*)(jk + (long)v * H);
    float4 a = r[0], b = r[1], c = r[2], d = r[3];
    float sum = a.x * w[0] + a.y * w[1] + a.z * w[2] + a.w * w[3]
              + b.x * w[4] + b.y * w[5] + b.z * w[6] + b.w * w[7]
              + c.x * w[8] + c.y * w[9] + c.z * w[10] + c.w * w[11]
              + d.x * w[12] + d.y * w[13] + d.z * w[14] + d.w * w[15];
    out[v] = sum + b0;
}

extern "C" void kernel_launch(void* const* d_in, const int* in_sizes, int n_in,
                              void* d_out, int out_size, void* d_ws, size_t ws_size,
                              hipStream_t stream) {
    const float* x    = (const float*)d_in[0];
    const void*  eidx = d_in[1];
    const float* W0   = (const float*)d_in[2];
    const float* Ws   = (const float*)d_in[3];
    const float* bs   = (const float*)d_in[4];
    const float* fc_w = (const float*)d_in[5];
    const float* fc_b = (const float*)d_in[6];

    int n = in_sizes[0] / F_IN;        // 100000
    int E = in_sizes[1] / 2;           // 3200000
    int L = in_sizes[4] / H;           // 10

    // workspace carve-up
    char* w = (char*)d_ws;
    size_t off = 0;
    int* rowstart    = (int*)(w + off); off += align256((size_t)(n + 1) * 4);
    float* dinv      = (float*)(w + off); off += align256((size_t)n * 4);
    int* bucketcnt   = (int*)(w + off); off += align256(512 * 4);
    int* bucketbase  = (int*)(w + off); off += align256(513 * 4);
    int* gcur        = (int*)(w + off); off += align256(512 * 4);
    int* flag64      = (int*)(w + off); off += align256(256);
    unsigned* stg    = (unsigned*)(w + off); off += align256((size_t)E * 4);
    int* ed          = (int*)(w + off); off += align256((size_t)E * 4);
    __hip_bfloat16* hwA = (__hip_bfloat16*)(w + off); off += align256((size_t)n * H * 2);
    __hip_bfloat16* hwB = (__hip_bfloat16*)(w + off); off += align256((size_t)n * H * 2);
    float* jk        = (float*)(w + off); off += align256((size_t)n * H * 4);

    int NB = (n + 255) / 256;          // 391 buckets of 256 nodes

    hipMemsetAsync(bucketcnt, 0, 512 * 4, stream);
    detect_kernel<<<1, 256, 0, stream>>>((const int*)eidx, flag64);
    bcount_kernel<<<512, 256, 0, stream>>>(eidx, E, flag64, n, bucketcnt);
    bscan_kernel<<<1, 512, 0, stream>>>(bucketcnt, NB, E, gcur, bucketbase);
    int SG = (E + 4095) / 4096;        // chunk <= 4096 <= SCH
    stage_kernel<<<SG, 256, 0, stream>>>(eidx, E, flag64, n, gcur, stg);
    fine_kernel<<<NB, 256, 0, stream>>>(stg, bucketbase, n, E, ed, rowstart, dinv);

    int ngrid = (n + NPB - 1) / NPB;   // 6250
    t0_kernel<<<ngrid, 256, 0, stream>>>(x, W0, dinv, hwA, n);

    __hip_bfloat16* cur = hwA;
    __hip_bfloat16* nxt = hwB;
    int agrid = (n + ANPB - 1) / ANPB; // 6250
    for (int l = 0; l < L; ++l) {
        const float* bias  = bs + (size_t)l * H;
        const float* Wnext = (l < L - 1) ? (Ws + (size_t)l * H * H) : nullptr;
        agg_kernel<<<agrid, 256, 0, stream>>>(ed, rowstart, dinv, cur, bias, Wnext,
                                              jk, nxt, n, (l == 0) ? 1 : 0,
                                              (l < L - 1) ? 1 : 0);
        __hip_bfloat16* t = cur; cur = nxt; nxt = t;
    }

    fc_kernel<<<NB, 256, 0, stream>>>(jk, fc_w, fc_b, (float*)d_out, n);
}

// Round 8
// 376.525 us; speedup vs baseline: 1.1240x; 1.1240x over previous
//
#include <hip/hip_runtime.h>
#include <hip/hip_bf16.h>

#define H 16
#define F_IN 58
#define NPB 16     // nodes per block in t0 (256 threads / 16 lanes)
#define SCH 4160   // max edges per stage chunk (LDS sort capacity)
#define ECAP 4096  // LDS edge-cache capacity in agg (64 nodes * avg 32 = 2048 typ)

static inline size_t align256(size_t x) { return (x + 255) & ~(size_t)255; }

__device__ inline float blo(unsigned u) { return __uint_as_float(u << 16); }
__device__ inline float bhi(unsigned u) { return __uint_as_float(u & 0xFFFF0000u); }
__device__ inline unsigned packbf(float a, float b) {
    unsigned ua = (unsigned)__bfloat16_as_ushort(__float2bfloat16(a));
    unsigned ub = (unsigned)__bfloat16_as_ushort(__float2bfloat16(b));
    return ua | (ub << 16);
}

// ---------- dtype detection: int64 vs int32 edge_index ----------
__global__ void detect_kernel(const int* eidx32, int* flag) {
    __shared__ int any;
    if (threadIdx.x == 0) any = 0;
    __syncthreads();
    int nz = 0;
    for (int j = threadIdx.x; j < 1024; j += 256)
        nz |= (eidx32[2 * j + 1] != 0);
    if (nz) atomicOr(&any, 1);
    __syncthreads();
    if (threadIdx.x == 0) *flag = (any == 0) ? 1 : 0;  // all-zero odd words -> int64
}

__device__ inline int load_idx(const void* eidx, long i, int is64) {
    if (is64) return (int)((const long long*)eidx)[i];
    return ((const int*)eidx)[i];
}

// ---------- bucket counts (391 bins of 256 nodes) via LDS histogram ----------
__global__ void bcount_kernel(const void* eidx, int E, const int* flag64,
                              int n, int* bucketcnt) {
    __shared__ int hist[512];
    int is64 = *flag64;
    int B = (n + 255) >> 8;
    int tid = threadIdx.x;
    for (int j = tid; j < B; j += 256) hist[j] = 0;
    __syncthreads();
    int stride = gridDim.x * blockDim.x;
    for (int i = blockIdx.x * blockDim.x + tid; i < E; i += stride) {
        int d = load_idx(eidx, (long)E + i, is64);
        atomicAdd(&hist[d >> 8], 1);
    }
    __syncthreads();
    for (int j = tid; j < B; j += 256)
        if (hist[j]) atomicAdd(&bucketcnt[j], hist[j]);
}

// ---------- exclusive scan of bucket counts (single block, B <= 512) ----------
__global__ void bscan_kernel(const int* bucketcnt, int B, int E,
                             int* gcur, int* bucketbase) {
    __shared__ int tmp[512];
    int tid = threadIdx.x;
    int val = (tid < B) ? bucketcnt[tid] : 0;
    tmp[tid] = val;
    __syncthreads();
    for (int off = 1; off < 512; off <<= 1) {
        int t = (tid >= off) ? tmp[tid - off] : 0;
        __syncthreads();
        tmp[tid] += t;
        __syncthreads();
    }
    if (tid < B) {
        int ex = tmp[tid] - val;
        gcur[tid] = ex;
        bucketbase[tid] = ex;
    }
    if (tid == 0) bucketbase[B] = E;
}

// ---------- stage: LDS counting-sort each chunk by bucket, write coalesced runs ----------
__global__ void stage_kernel(const void* eidx, int E, const int* flag64,
                             int n, int* gcur, unsigned* staging) {
    __shared__ unsigned sorted[SCH];
    __shared__ unsigned short sbuck[SCH];
    __shared__ int hist[512];
    __shared__ int hbase[512];
    __shared__ int lofs[512];
    __shared__ int cursor[512];
    __shared__ int ps[256];

    int is64 = *flag64;
    int tid = threadIdx.x;
    int chunk = (E + gridDim.x - 1) / gridDim.x;
    int s0 = blockIdx.x * chunk;
    int s1 = min(E, s0 + chunk);
    int c = s1 - s0;
    if (c <= 0) return;

    for (int j = tid; j < 512; j += 256) { hist[j] = 0; cursor[j] = 0; }
    __syncthreads();

    // pass A: per-chunk bucket histogram
    for (int i = s0 + tid; i < s1; i += 256) {
        int d = load_idx(eidx, (long)E + i, is64);
        atomicAdd(&hist[d >> 8], 1);
    }
    __syncthreads();

    // pass B: reserve global run per bucket
    for (int j = tid; j < 512; j += 256) {
        int cc = hist[j];
        hbase[j] = cc ? atomicAdd(&gcur[j], cc) : 0;
    }

    // pass C: exclusive scan of hist -> lofs (512 bins, 256 threads)
    int a0 = hist[2 * tid], a1 = hist[2 * tid + 1];
    ps[tid] = a0 + a1;
    __syncthreads();
    for (int off = 1; off < 256; off <<= 1) {
        int t = (tid >= off) ? ps[tid - off] : 0;
        __syncthreads();
        ps[tid] += t;
        __syncthreads();
    }
    int ex = ps[tid] - (a0 + a1);
    lofs[2 * tid] = ex;
    lofs[2 * tid + 1] = ex + a0;
    __syncthreads();

    // pass D: scatter into LDS in bucket-sorted order
    for (int i = s0 + tid; i < s1; i += 256) {
        int s = load_idx(eidx, i, is64);
        int d = load_idx(eidx, (long)E + i, is64);
        int b = d >> 8;
        int loc = lofs[b] + atomicAdd(&cursor[b], 1);
        sorted[loc] = (unsigned)s | ((unsigned)(d & 255) << 17);
        sbuck[loc] = (unsigned short)b;
    }
    __syncthreads();

    // pass E: linear LDS read, coalesced run writes to global
    for (int i = tid; i < c; i += 256) {
        int b = sbuck[i];
        staging[hbase[b] + (i - lofs[b])] = sorted[i];
    }
}

// ---------- per-bucket local hist + scan -> rowstart/dinv, node-sorted ed ----------
__global__ void fine_kernel(const unsigned* __restrict__ staging,
                            const int* __restrict__ bucketbase, int n, int E,
                            int* __restrict__ ed, int* __restrict__ rowstart,
                            float* __restrict__ dinv) {
    __shared__ int lcnt[256];
    __shared__ int lofs[256];
    __shared__ int lcur[256];
    int tid = threadIdx.x;
    int b = blockIdx.x;
    int node0 = b << 8;
    int start = bucketbase[b], end = bucketbase[b + 1];
    int cnt = end - start;
    lcnt[tid] = 0;
    lcur[tid] = 0;
    __syncthreads();
    for (int i = tid; i < cnt; i += 256) {
        unsigned w = staging[start + i];
        atomicAdd(&lcnt[w >> 17], 1);
    }
    __syncthreads();
    int val = lcnt[tid];
    lofs[tid] = val;
    __syncthreads();
    for (int off = 1; off < 256; off <<= 1) {
        int t = (tid >= off) ? lofs[tid - off] : 0;
        __syncthreads();
        lofs[tid] += t;
        __syncthreads();
    }
    int ex = lofs[tid] - val;
    __syncthreads();
    lofs[tid] = ex;
    __syncthreads();
    int node = node0 + tid;
    if (node < n) {
        rowstart[node] = start + ex;
        dinv[node] = rsqrtf((float)(val + 1));
    }
    if (node == 0) rowstart[n] = E;
    for (int i = tid; i < cnt; i += 256) {
        unsigned w = staging[start + i];
        int ld = (int)(w >> 17);
        int pos = start + lofs[ld] + atomicAdd(&lcur[ld], 1);
        ed[pos] = (int)(w & 0x1FFFFu);
    }
}

// ---------- layer 0 dense transform: hw0 = bf16(dinv * (x @ W0)) ----------
__global__ void t0_kernel(const float* __restrict__ x, const float* __restrict__ W0,
                          const float* __restrict__ dinv,
                          unsigned short* __restrict__ hw, int n) {
    __shared__ float Wl[F_IN * H];
    int tid = threadIdx.x;
    for (int j = tid; j < F_IN * H; j += 256) Wl[j] = W0[j];
    __syncthreads();
    int g = tid >> 4, f = tid & 15;
    int v = blockIdx.x * NPB + g;
    if (v >= n) return;
    const float* xr = x + (long)v * F_IN;
    float acc = 0.f;
#pragma unroll
    for (int k = 0; k < F_IN; ++k) acc += xr[k] * Wl[k * H + f];
    hw[v * H + f] = __bfloat16_as_ushort(__float2bfloat16(acc * dinv[v]));
}

// ---------- aggregation: 64 nodes/block, 4 lanes/node = 2 edge-slots x 2 feature-halves ----------
// hw holds dinv-scaled features (bf16); agg = dinv[v]*(sum_src hw[src] + hw[v])
__global__ __launch_bounds__(256) void agg_kernel(
    const int* __restrict__ ed, const int* __restrict__ rowstart,
    const float* __restrict__ dinv, const unsigned short* __restrict__ hw,
    const float* __restrict__ bias, const float* __restrict__ Wnext,
    unsigned short* __restrict__ jk, unsigned short* __restrict__ hw_next,
    int n, int first, int has_next) {
    __shared__ float Wl[H * H];
    __shared__ int eds[ECAP];
    __shared__ int rs[65];
    int tid = threadIdx.x;
    if (has_next) Wl[tid] = Wnext[tid];  // 256 threads == 16x16
    int node0 = blockIdx.x * 64;
    int nn = min(64, n - node0);         // nodes in this block (>=1)
    if (tid <= nn) rs[tid] = rowstart[node0 + tid];
    __syncthreads();
    int s0 = rs[0];
    int cnt = rs[nn] - s0;
    for (int i = tid; i < cnt && i < ECAP; i += 256) eds[i] = ed[s0 + i];
    __syncthreads();

    int g = tid >> 2, l = tid & 3;       // 64 nodes/block, 4 lanes/node
    int es = l & 1;                      // edge slot (parity)
    int fh = l >> 1;                     // feature half
    if (g >= nn) return;
    int v = node0 + g;
    int fb = fh * 8;                     // feature base (8 bf16 = 16B)

    float4 aA0 = make_float4(0.f, 0.f, 0.f, 0.f), aA1 = aA0;
    float4 aB0 = aA0, aB1 = aA0;
    int ls = rs[g] - s0, le = rs[g + 1] - s0;
    int base = ls;

    if (le <= ECAP) {                    // fast path: indices from LDS
        for (; base + 8 <= le; base += 8) {
            int t0 = eds[base + es],     t1 = eds[base + 2 + es];
            int t2 = eds[base + 4 + es], t3 = eds[base + 6 + es];
            uint4 q0 = *(const uint4*)(hw + t0 * H + fb);
            uint4 q1 = *(const uint4*)(hw + t1 * H + fb);
            uint4 q2 = *(const uint4*)(hw + t2 * H + fb);
            uint4 q3 = *(const uint4*)(hw + t3 * H + fb);
            aA0.x += blo(q0.x); aA0.y += bhi(q0.x); aA0.z += blo(q0.y); aA0.w += bhi(q0.y);
            aA1.x += blo(q0.z); aA1.y += bhi(q0.z); aA1.z += blo(q0.w); aA1.w += bhi(q0.w);
            aB0.x += blo(q1.x); aB0.y += bhi(q1.x); aB0.z += blo(q1.y); aB0.w += bhi(q1.y);
            aB1.x += blo(q1.z); aB1.y += bhi(q1.z); aB1.z += blo(q1.w); aB1.w += bhi(q1.w);
            aA0.x += blo(q2.x); aA0.y += bhi(q2.x); aA0.z += blo(q2.y); aA0.w += bhi(q2.y);
            aA1.x += blo(q2.z); aA1.y += bhi(q2.z); aA1.z += blo(q2.w); aA1.w += bhi(q2.w);
            aB0.x += blo(q3.x); aB0.y += bhi(q3.x); aB0.z += blo(q3.y); aB0.w += bhi(q3.y);
            aB1.x += blo(q3.z); aB1.y += bhi(q3.z); aB1.z += blo(q3.w); aB1.w += bhi(q3.w);
        }
        for (int i = base + es; i < le; i += 2) {
            uint4 q = *(const uint4*)(hw + eds[i] * H + fb);
            aA0.x += blo(q.x); aA0.y += bhi(q.x); aA0.z += blo(q.y); aA0.w += bhi(q.y);
            aA1.x += blo(q.z); aA1.y += bhi(q.z); aA1.z += blo(q.w); aA1.w += bhi(q.w);
        }
    } else {                             // fallback: indices from global (huge block)
        for (; base + 8 <= le; base += 8) {
            int t0 = ed[s0 + base + es],     t1 = ed[s0 + base + 2 + es];
            int t2 = ed[s0 + base + 4 + es], t3 = ed[s0 + base + 6 + es];
            uint4 q0 = *(const uint4*)(hw + t0 * H + fb);
            uint4 q1 = *(const uint4*)(hw + t1 * H + fb);
            uint4 q2 = *(const uint4*)(hw + t2 * H + fb);
            uint4 q3 = *(const uint4*)(hw + t3 * H + fb);
            aA0.x += blo(q0.x); aA0.y += bhi(q0.x); aA0.z += blo(q0.y); aA0.w += bhi(q0.y);
            aA1.x += blo(q0.z); aA1.y += bhi(q0.z); aA1.z += blo(q0.w); aA1.w += bhi(q0.w);
            aB0.x += blo(q1.x); aB0.y += bhi(q1.x); aB0.z += blo(q1.y); aB0.w += bhi(q1.y);
            aB1.x += blo(q1.z); aB1.y += bhi(q1.z); aB1.z += blo(q1.w); aB1.w += bhi(q1.w);
            aA0.x += blo(q2.x); aA0.y += bhi(q2.x); aA0.z += blo(q2.y); aA0.w += bhi(q2.y);
            aA1.x += blo(q2.z); aA1.y += bhi(q2.z); aA1.z += blo(q2.w); aA1.w += bhi(q2.w);
            aB0.x += blo(q3.x); aB0.y += bhi(q3.x); aB0.z += blo(q3.y); aB0.w += bhi(q3.y);
            aB1.x += blo(q3.z); aB1.y += bhi(q3.z); aB1.z += blo(q3.w); aB1.w += bhi(q3.w);
        }
        for (int i = base + es; i < le; i += 2) {
            uint4 q = *(const uint4*)(hw + ed[s0 + i] * H + fb);
            aA0.x += blo(q.x); aA0.y += bhi(q.x); aA0.z += blo(q.y); aA0.w += bhi(q.y);
            aA1.x += blo(q.z); aA1.y += bhi(q.z); aA1.z += blo(q.w); aA1.w += bhi(q.w);
        }
    }

    float val[8];
    val[0] = aA0.x + aB0.x; val[1] = aA0.y + aB0.y;
    val[2] = aA0.z + aB0.z; val[3] = aA0.w + aB0.w;
    val[4] = aA1.x + aB1.x; val[5] = aA1.y + aB1.y;
    val[6] = aA1.z + aB1.z; val[7] = aA1.w + aB1.w;

    // butterfly reduce across the 2 edge slots (lane ^1 within width 4)
#pragma unroll
    for (int j = 0; j < 8; ++j) val[j] += __shfl_xor(val[j], 1, 4);

    // self-loop + bias + relu
    uint4 qs = *(const uint4*)(hw + (size_t)v * H + fb);
    float slv[8] = { blo(qs.x), bhi(qs.x), blo(qs.y), bhi(qs.y),
                     blo(qs.z), bhi(qs.z), blo(qs.w), bhi(qs.w) };
    float4 b0 = *(const float4*)(bias + fb);
    float4 b1 = *(const float4*)(bias + fb + 4);
    float bv[8] = { b0.x, b0.y, b0.z, b0.w, b1.x, b1.y, b1.z, b1.w };
    float dv = dinv[v];
#pragma unroll
    for (int j = 0; j < 8; ++j)
        val[j] = fmaxf((val[j] + slv[j]) * dv + bv[j], 0.f);

    // jk running max in bf16 (es==0 lanes store 16B each; 2 lanes cover 32B row)
    if (es == 0) {
        uint4* jkp = (uint4*)(jk + (size_t)v * H + fb);
        float m[8];
#pragma unroll
        for (int j = 0; j < 8; ++j) m[j] = val[j];
        if (!first) {
            uint4 jo = *jkp;
            m[0] = fmaxf(m[0], blo(jo.x)); m[1] = fmaxf(m[1], bhi(jo.x));
            m[2] = fmaxf(m[2], blo(jo.y)); m[3] = fmaxf(m[3], bhi(jo.y));
            m[4] = fmaxf(m[4], blo(jo.z)); m[5] = fmaxf(m[5], bhi(jo.z));
            m[6] = fmaxf(m[6], blo(jo.w)); m[7] = fmaxf(m[7], bhi(jo.w));
        }
        uint4 st;
        st.x = packbf(m[0], m[1]); st.y = packbf(m[2], m[3]);
        st.z = packbf(m[4], m[5]); st.w = packbf(m[6], m[7]);
        *jkp = st;
    }

    // fused next-layer transform: out[f'] = sum_k val_all[k] * W[k][f']
    if (has_next) {
        float o[8] = {0.f, 0.f, 0.f, 0.f, 0.f, 0.f, 0.f, 0.f};
#pragma unroll
        for (int k = 0; k < 16; ++k) {
            float vk = __shfl(val[k & 7], (k >> 3) * 2, 4);
            float4 w0 = *(const float4*)(Wl + k * H + fb);
            float4 w1 = *(const float4*)(Wl + k * H + fb + 4);
            o[0] += vk * w0.x; o[1] += vk * w0.y; o[2] += vk * w0.z; o[3] += vk * w0.w;
            o[4] += vk * w1.x; o[5] += vk * w1.y; o[6] += vk * w1.z; o[7] += vk * w1.w;
        }
        if (es == 0) {
            uint4 st;
            st.x = packbf(o[0] * dv, o[1] * dv); st.y = packbf(o[2] * dv, o[3] * dv);
            st.z = packbf(o[4] * dv, o[5] * dv); st.w = packbf(o[6] * dv, o[7] * dv);
            *(uint4*)(hw_next + (size_t)v * H + fb) = st;
        }
    }
}

// ---------- final FC: out = jk @ fc_w + fc_b (jk in bf16) ----------
__global__ void fc_kernel(const unsigned short* __restrict__ jk,
                          const float* __restrict__ fc_w,
                          const float* __restrict__ fc_b, float* __restrict__ out, int n) {
    __shared__ float w[H];
    __shared__ float b0;
    if (threadIdx.x < H) w[threadIdx.x] = fc_w[threadIdx.x];
    if (threadIdx.x == 0) b0 = fc_b[0];
    __syncthreads();
    int v = blockIdx.x * 256 + threadIdx.x;
    if (v >= n) return;
    const uint4* r = (const uint4*)(jk + (size_t)v * H);
    uint4 a = r[0], b = r[1];
    float sum = blo(a.x) * w[0]  + bhi(a.x) * w[1]  + blo(a.y) * w[2]  + bhi(a.y) * w[3]
              + blo(a.z) * w[4]  + bhi(a.z) * w[5]  + blo(a.w) * w[6]  + bhi(a.w) * w[7]
              + blo(b.x) * w[8]  + bhi(b.x) * w[9]  + blo(b.y) * w[10] + bhi(b.y) * w[11]
              + blo(b.z) * w[12] + bhi(b.z) * w[13] + blo(b.w) * w[14] + bhi(b.w) * w[15];
    out[v] = sum + b0;
}

extern "C" void kernel_launch(void* const* d_in, const int* in_sizes, int n_in,
                              void* d_out, int out_size, void* d_ws, size_t ws_size,
                              hipStream_t stream) {
    const float* x    = (const float*)d_in[0];
    const void*  eidx = d_in[1];
    const float* W0   = (const float*)d_in[2];
    const float* Ws   = (const float*)d_in[3];
    const float* bs   = (const float*)d_in[4];
    const float* fc_w = (const float*)d_in[5];
    const float* fc_b = (const float*)d_in[6];

    int n = in_sizes[0] / F_IN;        // 100000
    int E = in_sizes[1] / 2;           // 3200000
    int L = in_sizes[4] / H;           // 10

    // workspace carve-up
    char* w = (char*)d_ws;
    size_t off = 0;
    int* rowstart    = (int*)(w + off); off += align256((size_t)(n + 1) * 4);
    float* dinv      = (float*)(w + off); off += align256((size_t)n * 4);
    int* bucketcnt   = (int*)(w + off); off += align256(512 * 4);
    int* bucketbase  = (int*)(w + off); off += align256(513 * 4);
    int* gcur        = (int*)(w + off); off += align256(512 * 4);
    int* flag64      = (int*)(w + off); off += align256(256);
    unsigned* stg    = (unsigned*)(w + off); off += align256((size_t)E * 4);
    int* ed          = (int*)(w + off); off += align256((size_t)E * 4);
    unsigned short* hwA = (unsigned short*)(w + off); off += align256((size_t)n * H * 2);
    unsigned short* hwB = (unsigned short*)(w + off); off += align256((size_t)n * H * 2);
    unsigned short* jk  = (unsigned short*)(w + off); off += align256((size_t)n * H * 2);

    int NB = (n + 255) / 256;          // 391 buckets of 256 nodes

    hipMemsetAsync(bucketcnt, 0, 512 * 4, stream);
    detect_kernel<<<1, 256, 0, stream>>>((const int*)eidx, flag64);
    bcount_kernel<<<512, 256, 0, stream>>>(eidx, E, flag64, n, bucketcnt);
    bscan_kernel<<<1, 512, 0, stream>>>(bucketcnt, NB, E, gcur, bucketbase);
    int SG = (E + 4095) / 4096;        // chunk <= 4096 <= SCH
    stage_kernel<<<SG, 256, 0, stream>>>(eidx, E, flag64, n, gcur, stg);
    fine_kernel<<<NB, 256, 0, stream>>>(stg, bucketbase, n, E, ed, rowstart, dinv);

    int ngrid = (n + NPB - 1) / NPB;   // 6250
    t0_kernel<<<ngrid, 256, 0, stream>>>(x, W0, dinv, hwA, n);

    unsigned short* cur = hwA;
    unsigned short* nxt = hwB;
    int agrid = (n + 63) / 64;         // 1563
    for (int l = 0; l < L; ++l) {
        const float* bias  = bs + (size_t)l * H;
        const float* Wnext = (l < L - 1) ? (Ws + (size_t)l * H * H) : nullptr;
        agg_kernel<<<agrid, 256, 0, stream>>>(ed, rowstart, dinv, cur, bias, Wnext,
                                              jk, nxt, n, (l == 0) ? 1 : 0,
                                              (l < L - 1) ? 1 : 0);
        unsigned short* t = cur; cur = nxt; nxt = t;
    }

    fc_kernel<<<NB, 256, 0, stream>>>(jk, fc_w, fc_b, (float*)d_out, n);
}